// Round 13
// baseline (277.902 us; speedup 1.0000x reference)
//
#include <hip/hip_runtime.h>

typedef unsigned short u16;
typedef unsigned int   u32;
typedef unsigned long long u64;
typedef __attribute__((ext_vector_type(8))) short short8;
typedef __attribute__((ext_vector_type(4))) float f32x4;

#define NN 2048
#define LDT 72

__device__ __forceinline__ float b2f(u16 u){ union { u32 i; float f; } x; x.i = ((u32)u)<<16; return x.f; }
__device__ __forceinline__ u16 f2b(float f){
  u32 u = __float_as_uint(f);
  u32 r = (u + 0x7fffu + ((u>>16)&1u)) >> 16;
  return (u16)r;
}
__device__ __forceinline__ float ldf(const void* p, size_t i, int bf){
  return bf ? b2f(((const u16*)p)[i]) : ((const float*)p)[i];
}
__device__ __forceinline__ void splitbf(float v, u16& h, u16& l){
  h = f2b(v);
  l = f2b(v - b2f(h));
}
__device__ __forceinline__ u64 shflx64(u64 x, int m){
  u32 lo = (u32)x, hi = (u32)(x>>32);
  lo = (u32)__shfl_xor((int)lo, m, 64);
  hi = (u32)__shfl_xor((int)hi, m, 64);
  return ((u64)hi<<32) | (u64)lo;
}

// 64x64 in-wave bit transpose: lane t holds column t (bit r = row r) -> row t
__device__ __forceinline__ u64 bittr64(u64 v, int t){
  const u64 MS[6] = {0x00000000FFFFFFFFULL, 0x0000FFFF0000FFFFULL, 0x00FF00FF00FF00FFULL,
                     0x0F0F0F0F0F0F0F0FULL, 0x3333333333333333ULL, 0x5555555555555555ULL};
#pragma unroll
  for (int s5 = 0; s5 < 6; ++s5){
    int jj = 32 >> s5;
    u64 pm = shflx64(v, jj);
    u64 M = MS[s5];
    if ((t & jj) == 0) v = (v &  M) | ((pm &  M) << jj);
    else               v = (v & ~M) | ((pm & ~M) >> jj);
  }
  return v;
}

// ---------------- diagnostic sentinel (f32 out) ------------------------------
__global__ __launch_bounds__(256) void sentinel_kernel(float* __restrict__ out, float val){
  int g = blockIdx.x*256 + threadIdx.x;
  if (g < NN*64) out[g] = val;
}

// ---------------- dtype probe (parallel): fp32 words are 0 / 0x3F800000 -----
__global__ __launch_bounds__(256) void probe_kernel(const u32* __restrict__ ap, int* __restrict__ flag){
  int i = blockIdx.x*256 + threadIdx.x;   // 65536 words
  u32 w = ap[i];
  if (w != 0u && w != 0x3F800000u) atomicOr(flag, 1);
}

// ---------------- fused input processing: csc | negbits+tr0 | prep ----------
struct InputArgs {
  const void *Ap, *An, *x;
  int *ap_cnt, *ap_idx;
  u64 *last, *uni;
  u64* rowb0; int* deg0;      // stage-0 row bits + degree (fused bitstep 0)
  float* xf;
  const void *wl1,*bl1,*wl2,*bl2,*wl3,*bl3,*wg1,*bg1,*wg2,*bg2,*wg3,*bg3,*wg4,*bg4,*wg5,*bg5,*wg6,*bg6;
  float *tl1,*tg1,*tl2,*tg2,*tl3,*tg3,*tg4,*tg5,*tg6;
  float *obl1,*obg1,*obl2,*obg2,*obl3,*obg3,*obg4,*obg5,*obg6;
  const int* flag;
};

__global__ __launch_bounds__(256) void input_kernel(InputArgs a){
  int bf = *a.flag;
  int b = blockIdx.x;
  if (b < 16384){
    size_t e = (size_t)b*256 + threadIdx.x;   // e = k*2048 + j
    int k = (int)(e >> 11), j = (int)(e & 2047);
    if (ldf(a.Ap, e, bf) > 0.f){
      int p = atomicAdd(&a.ap_cnt[j], 1);
      if (p < 64) a.ap_idx[j*64 + p] = k;
    }
  } else if (b < 16640){
    int g = (b - 16384)*256 + threadIdx.x;    // 65536; wave holds 64 consecutive j, same w
    int j = g & 2047, w = g >> 11;
    int lane = threadIdx.x & 63;
    u64 bits = 0;
    for (int bb = 0; bb < 64; ++bb){
      float v = ldf(a.An, (size_t)(w*64 + bb)*NN + j, bf);
      bits |= (u64)(v > 0.f) << bb;
    }
    a.last[(size_t)j*32 + w] = bits;
    a.uni [(size_t)j*32 + w] = bits;
    // fused bitstep 0: transpose the 64x64 tile in-wave, emit rowb[0] + deg[0]
    u64 v = bittr64(bits, lane);
    a.rowb0[(size_t)(w*64 + lane)*32 + (j >> 6)] = v;
    atomicAdd(&a.deg0[w*64 + lane], (int)__popcll(v));
  } else {
    int t = (b - 16640)*256 + threadIdx.x;    // 131072 threads
    for (size_t i = t; i < (size_t)NN*512; i += 131072) a.xf[i] = ldf(a.x, i, bf);
    if (t < 256*512){ int n = t>>9, k = t&511; a.tl1[t] = ldf(a.wl1, (size_t)k*256 + n, bf); }
    if (t < 256*256){ int n = t>>8, k = t&255; a.tg1[t] = ldf(a.wg1, (size_t)k*256 + n, bf); }
    if (t <  64*256){ int n = t>>8, k = t&255; a.tl2[t] = (n < 62) ? ldf(a.wl2, (size_t)k*62 + n, bf) : 0.f; }
    if (t <  64*64){
      int n = t>>6, k = t&63;
      a.tg2[t] = (n < 62 && k < 62) ? ldf(a.wg2, (size_t)k*62 + n, bf) : 0.f;
      a.tl3[t] = (k < 62) ? ldf(a.wl3, (size_t)k*64 + n, bf) : 0.f;
      a.tg3[t] = ldf(a.wg3, (size_t)k*64 + n, bf);
      a.tg4[t] = ldf(a.wg4, (size_t)k*64 + n, bf);
      a.tg5[t] = ldf(a.wg5, (size_t)k*64 + n, bf);
      a.tg6[t] = ldf(a.wg6, (size_t)k*64 + n, bf);
    }
    if (t < 256){ a.obl1[t] = ldf(a.bl1, t, bf); a.obg1[t] = ldf(a.bg1, t, bf); }
    if (t < 64){
      a.obl2[t] = (t < 62) ? ldf(a.bl2, t, bf) : 0.f;
      a.obg2[t] = (t < 62) ? ldf(a.bg2, t, bf) : 0.f;
      a.obl3[t] = ldf(a.bl3, t, bf);
      a.obg3[t] = ldf(a.bg3, t, bf);
      a.obg4[t] = ldf(a.bg4, t, bf);
      a.obg5[t] = ldf(a.bg5, t, bf);
      a.obg6[t] = ldf(a.bg6, t, bf);
    }
  }
}

// --------------- bit expansion (coalesced, 1 wave per column j) -------------
struct ExpArgs { const int *cnt, *idx; const u64* src; u64* dst; const u64* uniIn; u64* uniOut; };
struct TrArgs  { const u64* uni; u64* rowb; int* deg; };

__device__ __forceinline__ void exp_blocks(const ExpArgs& ea, int eb){
  int wave = threadIdx.x >> 6, lane = threadIdx.x & 63;
  int j = eb*4 + wave;                     // eb in [0,512)
  int c = ea.cnt[j]; c = (c > 64) ? 64 : c;
  const int* lst = ea.idx + j*64;
  int wi = lane & 31, half = lane >> 5;
  u64 acc = 0;
  for (int s = half; s < c; s += 2)
    acc |= ea.src[(size_t)lst[s]*32 + wi]; // 32-lane coalesced 256B column read
  acc |= shflx64(acc, 32);
  if (lane < 32){
    ea.dst   [(size_t)j*32 + wi] = acc;
    ea.uniOut[(size_t)j*32 + wi] = ea.uniIn[(size_t)j*32 + wi] | acc;
  }
}

__device__ __forceinline__ void tr_blocks(const TrArgs& ta, int eb){
  int uid = eb*4 + (threadIdx.x >> 6);     // eb in [0,256), uid in [0,1024)
  int wi = uid >> 5, wj = uid & 31;
  int t = threadIdx.x & 63;
  u64 u = ta.uni[(size_t)(wj*64 + t)*32 + wi];
  u64 v = bittr64(u, t);
  ta.rowb[(size_t)(wi*64 + t)*32 + wj] = v;
  atomicAdd(&ta.deg[wi*64 + t], (int)__popcll(v));
}

struct Piggy { ExpArgs ea; TrArgs ta; int nexp, ntr; };
__device__ __forceinline__ void piggy_blocks(const Piggy& pg, int eb){
  if (eb < pg.nexp) exp_blocks(pg.ea, eb);
  else if (eb < pg.nexp + pg.ntr) tr_blocks(pg.ta, eb - pg.nexp);
}

#define MFMA_BF16 __builtin_amdgcn_mfma_f32_16x16x32_bf16

// --------------- split-bf16 MFMA GEMM: C[i][n] = sum_k A[i][k]*Bt[n][k] -----
// MODE 0: + bias[n] ; MODE 1: * 1/sqrt(deg[i]+1)
template<int MODE>
__device__ __forceinline__ void mgemm_core(u16* __restrict__ Ah, u16* __restrict__ Al,
                                           u16* __restrict__ Bh, u16* __restrict__ Bl,
                                           const float* __restrict__ A, const float* __restrict__ Bt,
                                           int N, int K,
                                           const float* __restrict__ bias, const int* __restrict__ deg,
                                           float* __restrict__ outF, int m0, int n0){
  const int tid = threadIdx.x;
  const int wave = tid >> 6, lane = tid & 63;
  const int wm = (wave>>1)*32, wn = (wave&1)*32;
  const int q = lane >> 4, l16 = lane & 15;
  f32x4 acc00 = {}, acc01 = {}, acc10 = {}, acc11 = {};
  const int sr = tid >> 2, sc = (tid & 3)*16;
  for (int k0 = 0; k0 < K; k0 += 64){
    const float* Ag = A  + (size_t)(m0+sr)*K + k0 + sc;
    const float* Bg = Bt + (size_t)(n0+sr)*K + k0 + sc;
#pragma unroll
    for (int v4 = 0; v4 < 4; ++v4){
      float4 av = ((const float4*)Ag)[v4];
      float4 bv = ((const float4*)Bg)[v4];
      int o = sr*LDT + sc + v4*4;
      splitbf(av.x, Ah[o+0], Al[o+0]); splitbf(av.y, Ah[o+1], Al[o+1]);
      splitbf(av.z, Ah[o+2], Al[o+2]); splitbf(av.w, Ah[o+3], Al[o+3]);
      splitbf(bv.x, Bh[o+0], Bl[o+0]); splitbf(bv.y, Bh[o+1], Bl[o+1]);
      splitbf(bv.z, Bh[o+2], Bl[o+2]); splitbf(bv.w, Bh[o+3], Bl[o+3]);
    }
    __syncthreads();
#pragma unroll
    for (int ks = 0; ks < 2; ++ks){
      const int kb = ks*32 + q*8;
      short8 ah0 = *(const short8*)&Ah[(wm      + l16)*LDT + kb];
      short8 al0 = *(const short8*)&Al[(wm      + l16)*LDT + kb];
      short8 ah1 = *(const short8*)&Ah[(wm + 16 + l16)*LDT + kb];
      short8 al1 = *(const short8*)&Al[(wm + 16 + l16)*LDT + kb];
      short8 bh0 = *(const short8*)&Bh[(wn      + l16)*LDT + kb];
      short8 bl0 = *(const short8*)&Bl[(wn      + l16)*LDT + kb];
      short8 bh1 = *(const short8*)&Bh[(wn + 16 + l16)*LDT + kb];
      short8 bl1 = *(const short8*)&Bl[(wn + 16 + l16)*LDT + kb];
      acc00 = MFMA_BF16(ah0, bh0, acc00, 0, 0, 0);
      acc00 = MFMA_BF16(ah0, bl0, acc00, 0, 0, 0);
      acc00 = MFMA_BF16(al0, bh0, acc00, 0, 0, 0);
      acc01 = MFMA_BF16(ah0, bh1, acc01, 0, 0, 0);
      acc01 = MFMA_BF16(ah0, bl1, acc01, 0, 0, 0);
      acc01 = MFMA_BF16(al0, bh1, acc01, 0, 0, 0);
      acc10 = MFMA_BF16(ah1, bh0, acc10, 0, 0, 0);
      acc10 = MFMA_BF16(ah1, bl0, acc10, 0, 0, 0);
      acc10 = MFMA_BF16(al1, bh0, acc10, 0, 0, 0);
      acc11 = MFMA_BF16(ah1, bh1, acc11, 0, 0, 0);
      acc11 = MFMA_BF16(ah1, bl1, acc11, 0, 0, 0);
      acc11 = MFMA_BF16(al1, bh1, acc11, 0, 0, 0);
    }
    __syncthreads();
  }
#pragma unroll
  for (int mi = 0; mi < 2; ++mi)
#pragma unroll
  for (int ni = 0; ni < 2; ++ni){
    f32x4 a = (mi == 0) ? ((ni == 0) ? acc00 : acc01) : ((ni == 0) ? acc10 : acc11);
#pragma unroll
    for (int r = 0; r < 4; ++r){
      int i = m0 + wm + mi*16 + q*4 + r;
      int n = n0 + wn + ni*16 + l16;
      float v = a[r];
      if constexpr (MODE == 0) v += bias[n];
      else                     v *= 1.0f / sqrtf((float)(deg[i] + 1));
      outF[(size_t)i*N + n] = v;
    }
  }
}

// --------------- split-K bitmask-MFMA aggregation (partials) ----------------
template<int F>
__device__ __forceinline__ void maggp_core(const float* __restrict__ zs, const u64* __restrict__ rowb,
                                           float* __restrict__ p, int m0, int n0, int kc0, int KCH){
  const int tid = threadIdx.x;
  const int wave = tid >> 6, lane = tid & 63;
  const int wm = (wave>>1)*32, wn = (wave&1)*32;
  const int q = lane >> 4, l16 = lane & 15;
  f32x4 acc00 = {}, acc01 = {}, acc10 = {}, acc11 = {};
  for (int k0 = kc0; k0 < kc0 + KCH; k0 += 64){
    const int wd = k0 >> 6;
    u64 w0 = rowb[(size_t)(m0 + wm      + l16)*32 + wd];
    u64 w1 = rowb[(size_t)(m0 + wm + 16 + l16)*32 + wd];
#pragma unroll
    for (int ks = 0; ks < 2; ++ks){
      const int kk = ks*32 + q*8;
      u32 by0 = (u32)(w0 >> kk) & 0xFFu;
      u32 by1 = (u32)(w1 >> kk) & 0xFFu;
      short8 a0, a1;
#pragma unroll
      for (int j = 0; j < 8; ++j){
        a0[j] = (short)(((by0 >> j) & 1u) ? 0x3F80 : 0);
        a1[j] = (short)(((by1 >> j) & 1u) ? 0x3F80 : 0);
      }
      const float* B0 = zs + (size_t)(k0 + kk)*F + n0;
      short8 bh0, bl0, bh1, bl1;
#pragma unroll
      for (int j = 0; j < 8; ++j){
        u16 hh, ll;
        splitbf(B0[(size_t)j*F + wn      + l16], hh, ll); bh0[j] = (short)hh; bl0[j] = (short)ll;
        splitbf(B0[(size_t)j*F + wn + 16 + l16], hh, ll); bh1[j] = (short)hh; bl1[j] = (short)ll;
      }
      acc00 = MFMA_BF16(a0, bh0, acc00, 0, 0, 0);
      acc00 = MFMA_BF16(a0, bl0, acc00, 0, 0, 0);
      acc01 = MFMA_BF16(a0, bh1, acc01, 0, 0, 0);
      acc01 = MFMA_BF16(a0, bl1, acc01, 0, 0, 0);
      acc10 = MFMA_BF16(a1, bh0, acc10, 0, 0, 0);
      acc10 = MFMA_BF16(a1, bl0, acc10, 0, 0, 0);
      acc11 = MFMA_BF16(a1, bh1, acc11, 0, 0, 0);
      acc11 = MFMA_BF16(a1, bl1, acc11, 0, 0, 0);
    }
  }
#pragma unroll
  for (int mi = 0; mi < 2; ++mi)
#pragma unroll
  for (int ni = 0; ni < 2; ++ni){
    f32x4 a = (mi == 0) ? ((ni == 0) ? acc00 : acc01) : ((ni == 0) ? acc10 : acc11);
#pragma unroll
    for (int r = 0; r < 4; ++r){
      int i = m0 + wm + mi*16 + q*4 + r;
      int n = n0 + wn + ni*16 + l16;
      p[(size_t)i*F + n] = a[r];
    }
  }
}

// --------------- split-K reduce + GCN epilogue ------------------------------
template<int F>
__device__ __forceinline__ void magge_core(const float* __restrict__ part, const float* __restrict__ zs,
                                           const float* __restrict__ h, const float* __restrict__ bias,
                                           const int* __restrict__ deg, int KS, float wgt, int doRelu,
                                           float* __restrict__ outF, float* __restrict__ outD, int g){
  int n = g & (F - 1);
  int i = g / F;
  float y = 0.f;
  for (int s = 0; s < KS; ++s) y += part[(size_t)s*NN*F + g];
  float di = 1.0f / sqrtf((float)(deg[i] + 1));
  float o = di*(y + zs[g]) + bias[n];
  if (doRelu) o = fmaxf(o, 0.f);
  float xn = h[g] + wgt*o;
  outF[g] = xn;
  if (outD) outD[g] = xn;
}

// =================== standalone wrappers =====================================
template<int F>
__global__ __launch_bounds__(256) void maggp_kernel(const float* zs, const u64* rowb, float* part, int KCH){
  maggp_core<F>(zs, rowb, part + (size_t)blockIdx.z*NN*F,
                blockIdx.x*64, blockIdx.y*64, blockIdx.z*KCH, KCH);
}
template<int F>
__global__ __launch_bounds__(256) void magge_kernel(const float* part, const float* zs, const float* h,
                                                    const float* bias, const int* deg,
                                                    int KS, float wgt, int doRelu,
                                                    float* outF, float* outD){
  magge_core<F>(part, zs, h, bias, deg, KS, wgt, doRelu, outF, outD, blockIdx.x*256 + threadIdx.x);
}

// ===== 16-row block primitives (128-block fused epi+GEMM kernels, F=64) =====
// block: 16 m-rows, 4 waves; wave w owns n-cols [16w,16w+16); nq = wave*16+l16

#define GEMM16(ACC)                                                        \
  _Pragma("unroll")                                                        \
  for (int ks = 0; ks < 2; ++ks){                                          \
    const int kb = ks*32 + q*8;                                            \
    short8 ah = *(const short8*)&Ah[l16*LDT + kb];                         \
    short8 al = *(const short8*)&Al[l16*LDT + kb];                         \
    short8 bh = *(const short8*)&Bh[nq*LDT + kb];                          \
    short8 bl = *(const short8*)&Bl[nq*LDT + kb];                          \
    ACC = MFMA_BF16(ah, bh, ACC, 0, 0, 0);                                 \
    ACC = MFMA_BF16(ah, bl, ACC, 0, 0, 0);                                 \
    ACC = MFMA_BF16(al, bh, ACC, 0, 0, 0);                                 \
  }

#define STAGE_B64(BT)                                                      \
  {                                                                        \
    const int sr = tid >> 2, sc = (tid & 3)*16;                            \
    const float* Bg = (BT) + (size_t)sr*64 + sc;                           \
    _Pragma("unroll")                                                      \
    for (int v4 = 0; v4 < 4; ++v4){                                        \
      float4 bv = ((const float4*)Bg)[v4];                                 \
      int o = sr*LDT + sc + v4*4;                                          \
      splitbf(bv.x, Bh[o+0], Bl[o+0]); splitbf(bv.y, Bh[o+1], Bl[o+1]);    \
      splitbf(bv.z, Bh[o+2], Bl[o+2]); splitbf(bv.w, Bh[o+3], Bl[o+3]);    \
    }                                                                      \
  }

// split-K epilogue for 16 rows: x = h + wgt*relu((sum part + zs)*dinv + bias)
// writes xF and stashes split-bf16 x into Ah/Al (coalesced part reads)
template<int KS>
__device__ __forceinline__ void epi16(const float* __restrict__ part, const float* __restrict__ zsP,
                                      const float* __restrict__ hP, const float* __restrict__ biasP,
                                      const int* __restrict__ degP, float wgt,
                                      float* __restrict__ xF, u16* __restrict__ Ah, u16* __restrict__ Al,
                                      int m0, int tid){
#pragma unroll
  for (int pp = 0; pp < 4; ++pp){
    int idx = pp*256 + tid;            // 0..1023 = 16 rows x 64 n
    int il = idx >> 6, n = idx & 63;
    int i = m0 + il;
    size_t g = (size_t)i*64 + n;
    float y = 0.f;
#pragma unroll
    for (int s = 0; s < KS; ++s) y += part[(size_t)s*NN*64 + g];
    float di = 1.0f / sqrtf((float)(degP[i] + 1));
    float o = fmaxf(di*(y + zsP[g]) + biasP[n], 0.f);
    float xv = hP[g] + wgt*o;
    xF[g] = xv;
    u16 hh, ll; splitbf(xv, hh, ll);
    Ah[il*LDT + n] = hh;
    Al[il*LDT + n] = ll;
  }
}

// --------------- fused: prev-stage epilogue + single GEMM (K=64) ------------
__global__ __launch_bounds__(256) void epieg1_16(const float* __restrict__ part, const float* __restrict__ zsP,
                                                 const float* __restrict__ hP, const float* __restrict__ biasP,
                                                 const int* __restrict__ degP, float wgt,
                                                 float* __restrict__ xF,
                                                 const float* __restrict__ BtG, const int* __restrict__ degN,
                                                 float* __restrict__ zsOut){
  __shared__ u16 Ah[16*LDT], Al[16*LDT], Bh[64*LDT], Bl[64*LDT];
  const int m0 = blockIdx.x*16;
  const int tid = threadIdx.x;
  const int wave = tid >> 6, lane = tid & 63;
  const int q = lane >> 4, l16 = lane & 15;
  const int nq = wave*16 + l16;
  epi16<4>(part, zsP, hP, biasP, degP, wgt, xF, Ah, Al, m0, tid);
  STAGE_B64(BtG)
  __syncthreads();
  f32x4 z = {};
  GEMM16(z)
  const int i0 = m0 + q*4;
#pragma unroll
  for (int r = 0; r < 4; ++r)
    zsOut[(size_t)(i0+r)*64 + nq] = z[r] * (1.0f / sqrtf((float)(degN[i0+r] + 1)));
}

// --------------- fused: prev-stage epilogue + DUAL GEMM (K=64) --------------
__global__ __launch_bounds__(256) void epieg2_16(const float* __restrict__ part, const float* __restrict__ zsP,
                                                 const float* __restrict__ hP, const float* __restrict__ biasP,
                                                 const int* __restrict__ degP, float wgt,
                                                 float* __restrict__ xF,
                                                 const float* __restrict__ Bt1, const float* __restrict__ bias1,
                                                 const float* __restrict__ Bt2, const int* __restrict__ degN,
                                                 float* __restrict__ hOut, float* __restrict__ zsOut){
  __shared__ u16 Ah[16*LDT], Al[16*LDT], Bh[64*LDT], Bl[64*LDT];
  const int m0 = blockIdx.x*16;
  const int tid = threadIdx.x;
  const int wave = tid >> 6, lane = tid & 63;
  const int q = lane >> 4, l16 = lane & 15;
  const int nq = wave*16 + l16;
  epi16<4>(part, zsP, hP, biasP, degP, wgt, xF, Ah, Al, m0, tid);
  STAGE_B64(Bt1)
  __syncthreads();
  f32x4 h = {};
  GEMM16(h)
  __syncthreads();       // Ah reads done before restash
#pragma unroll
  for (int r = 0; r < 4; ++r){
    int il = q*4 + r;
    float hv = h[r] + bias1[nq];
    hOut[(size_t)(m0+il)*64 + nq] = hv;
    u16 hh, ll; splitbf(hv, hh, ll);
    Ah[il*LDT + nq] = hh;
    Al[il*LDT + nq] = ll;
  }
  STAGE_B64(Bt2)
  __syncthreads();
  f32x4 z = {};
  GEMM16(z)
  const int i0 = m0 + q*4;
#pragma unroll
  for (int r = 0; r < 4; ++r)
    zsOut[(size_t)(i0+r)*64 + nq] = z[r] * (1.0f / sqrtf((float)(degN[i0+r] + 1)));
}

// =================== hybrid co-launch kernels ================================
__global__ __launch_bounds__(256) void hyb_g0(const float* A, const float* Bt, const float* bias,
                                              float* outF, Piggy pg){
  __shared__ u16 Ah[64*LDT], Al[64*LDT], Bh[64*LDT], Bl[64*LDT];
  int b = blockIdx.x;
  if (b < 128) mgemm_core<0>(Ah, Al, Bh, Bl, A, Bt, 256, 512, bias, nullptr, outF, (b>>2)*64, (b&3)*64);
  else         piggy_blocks(pg, b - 128);
}
__global__ __launch_bounds__(256) void hyb_g1(const float* A, const float* Bt, const int* deg,
                                              float* outF, Piggy pg){
  __shared__ u16 Ah[64*LDT], Al[64*LDT], Bh[64*LDT], Bl[64*LDT];
  int b = blockIdx.x;
  if (b < 128) mgemm_core<1>(Ah, Al, Bh, Bl, A, Bt, 256, 256, nullptr, deg, outF, (b>>2)*64, (b&3)*64);
  else         piggy_blocks(pg, b - 128);
}
__global__ __launch_bounds__(256) void hyb_p0(const float* zs, const u64* rowb, float* part, Piggy pg){
  int b = blockIdx.x;
  if (b < 512){
    int bx = b & 31, by = (b >> 5) & 3, bz = b >> 7;
    maggp_core<256>(zs, rowb, part + (size_t)bz*NN*256, bx*64, by*64, bz*512, 512);
  } else piggy_blocks(pg, b - 512);
}
__global__ __launch_bounds__(256) void hyb_e0(const float* part, const float* zs, const float* h,
                                              const float* bias, const int* deg, float* outF, Piggy pg){
  int b = blockIdx.x;
  if (b < 2048) magge_core<256>(part, zs, h, bias, deg, 4, 1.0f, 1, outF, nullptr, b*256 + threadIdx.x);
  else          piggy_blocks(pg, b - 2048);
}
// stage-1 dual GEMM, 16-row blocks (128 host) || piggy
__global__ __launch_bounds__(256) void hyb_g2_16(const float* __restrict__ A, const float* __restrict__ Bt1,
                                                 const float* __restrict__ bias1,
                                                 const float* __restrict__ Bt2, const int* __restrict__ deg,
                                                 float* __restrict__ hOut, float* __restrict__ zsOut,
                                                 Piggy pg){
  __shared__ u16 Ah[16*LDT], Al[16*LDT], Bh[64*LDT], Bl[64*LDT];
  int b = blockIdx.x;
  if (b >= 128){ piggy_blocks(pg, b - 128); return; }
  const int m0 = b*16;
  const int tid = threadIdx.x;
  const int wave = tid >> 6, lane = tid & 63;
  const int q = lane >> 4, l16 = lane & 15;
  const int nq = wave*16 + l16;
  f32x4 acc = {};
  for (int k0 = 0; k0 < 256; k0 += 64){
    { // stage A 16x64
      const int ar = tid >> 4, ac = (tid & 15)*4;
      float4 av = *(const float4*)&A[(size_t)(m0+ar)*256 + k0 + ac];
      int o = ar*LDT + ac;
      splitbf(av.x, Ah[o+0], Al[o+0]); splitbf(av.y, Ah[o+1], Al[o+1]);
      splitbf(av.z, Ah[o+2], Al[o+2]); splitbf(av.w, Ah[o+3], Al[o+3]);
    }
    { // stage B 64x64 from Bt1 (row-stride 256)
      const int sr = tid >> 2, sc = (tid & 3)*16;
      const float* Bg = Bt1 + (size_t)sr*256 + k0 + sc;
#pragma unroll
      for (int v4 = 0; v4 < 4; ++v4){
        float4 bv = ((const float4*)Bg)[v4];
        int o = sr*LDT + sc + v4*4;
        splitbf(bv.x, Bh[o+0], Bl[o+0]); splitbf(bv.y, Bh[o+1], Bl[o+1]);
        splitbf(bv.z, Bh[o+2], Bl[o+2]); splitbf(bv.w, Bh[o+3], Bl[o+3]);
      }
    }
    __syncthreads();
    GEMM16(acc)
    __syncthreads();
  }
#pragma unroll
  for (int r = 0; r < 4; ++r){
    int il = q*4 + r;
    float hv = acc[r] + bias1[nq];
    hOut[(size_t)(m0+il)*64 + nq] = hv;
    u16 hh, ll; splitbf(hv, hh, ll);
    Ah[il*LDT + nq] = hh;
    Al[il*LDT + nq] = ll;
  }
  STAGE_B64(Bt2)
  __syncthreads();
  f32x4 z = {};
  GEMM16(z)
  const int i0 = m0 + q*4;
#pragma unroll
  for (int r = 0; r < 4; ++r)
    zsOut[(size_t)(i0+r)*64 + nq] = z[r] * (1.0f / sqrtf((float)(deg[i0+r] + 1)));
}
__global__ __launch_bounds__(256) void hyb_p1(const float* zs, const u64* rowb, float* part, Piggy pg){
  int b = blockIdx.x;
  if (b < 128){
    int bx = b & 31, bz = b >> 5;     // 32m x 4z, KCH=512
    maggp_core<64>(zs, rowb, part + (size_t)bz*NN*64, bx*64, 0, bz*512, 512);
  } else piggy_blocks(pg, b - 128);
}

static inline char* wso(void* ws, size_t& off, size_t bytes){
  char* p = (char*)ws + off;
  off += (bytes + 255) & ~(size_t)255;
  return p;
}

extern "C" void kernel_launch(void* const* d_in, const int* in_sizes, int n_in,
                              void* d_out, int out_size, void* d_ws, size_t ws_size,
                              hipStream_t stream){
  // ---- regression guards ----
  static const int EXP_SIZES[21] = {
    2048*512, 2048*2048, 2048*2048,
    512*256, 256, 256*62, 62, 62*64, 64,
    256*256, 256, 62*62, 62, 64*64, 64,
    64*64, 64, 64*64, 64, 64*64, 64
  };
  float sentinel = 0.f;
  if (n_in != 21) sentinel = 8800000.f;
  if (sentinel == 0.f){
    for (int i = 0; i < 21; ++i)
      if (in_sizes[i] != EXP_SIZES[i]){ sentinel = 100000.f*(float)(i+1); break; }
  }
  if (sentinel == 0.f && out_size != 2048*64) sentinel = 6600000.f;

  // ---- workspace layout (zeroed prefix: dflag|ap_cnt|deg6) ----
  size_t off = 0;
  int*   dflag  = (int*)  wso(d_ws, off, 256);
  int*   ap_cnt = (int*)  wso(d_ws, off, NN*4);
  int*   deg6   = (int*)  wso(d_ws, off, (size_t)6*NN*4);
  size_t zero_bytes = off;
  int*   ap_idx = (int*)  wso(d_ws, off, NN*64*4);
  u64*   colA   = (u64*)  wso(d_ws, off, (size_t)NN*32*8);
  u64*   colB   = (u64*)  wso(d_ws, off, (size_t)NN*32*8);
  u64*   colU   = (u64*)  wso(d_ws, off, (size_t)NN*32*8);
  u64*   colV   = (u64*)  wso(d_ws, off, (size_t)NN*32*8);
  u64*   rowb6  = (u64*)  wso(d_ws, off, (size_t)6*NN*32*8);
  float* xf     = (float*)wso(d_ws, off, (size_t)NN*512*4);
  float* part   = (float*)wso(d_ws, off, (size_t)16*NN*64*4);   // 8 MB split-K partials
  float *tl1 = (float*)wso(d_ws, off, 256*512*4), *tg1 = (float*)wso(d_ws, off, 256*256*4);
  float *tl2 = (float*)wso(d_ws, off,  64*256*4), *tg2 = (float*)wso(d_ws, off,  64*64*4);
  float *tl3 = (float*)wso(d_ws, off,   64*64*4), *tg3 = (float*)wso(d_ws, off,  64*64*4);
  float *tg4 = (float*)wso(d_ws, off,   64*64*4), *tg5 = (float*)wso(d_ws, off,  64*64*4);
  float *tg6 = (float*)wso(d_ws, off,   64*64*4);
  float *obl1 = (float*)wso(d_ws, off, 256*4), *obg1 = (float*)wso(d_ws, off, 256*4);
  float *obl2 = (float*)wso(d_ws, off, 64*4),  *obg2 = (float*)wso(d_ws, off, 64*4);
  float *obl3 = (float*)wso(d_ws, off, 64*4),  *obg3 = (float*)wso(d_ws, off, 64*4);
  float *obg4 = (float*)wso(d_ws, off, 64*4),  *obg5 = (float*)wso(d_ws, off, 64*4);
  float *obg6 = (float*)wso(d_ws, off, 64*4);
  float* hF   = (float*)wso(d_ws, off, (size_t)NN*256*4);
  float* zs   = (float*)wso(d_ws, off, (size_t)NN*256*4);
  float* xF   = (float*)wso(d_ws, off, (size_t)NN*256*4);

  if (sentinel == 0.f && off > ws_size) sentinel = 7700000.f;

  if (sentinel != 0.f){
    sentinel_kernel<<<(NN*64 + 255)/256, 256, 0, stream>>>((float*)d_out, sentinel);
    return;
  }

  const void* x_in = d_in[0];
  const void* An   = d_in[1];
  const void* Ap   = d_in[2];

  hipMemsetAsync(d_ws, 0, zero_bytes, stream);   // dflag + ap_cnt + deg6
  probe_kernel<<<256, 256, 0, stream>>>((const u32*)Ap, dflag);

  InputArgs ia;
  ia.Ap = Ap; ia.An = An; ia.x = x_in;
  ia.ap_cnt = ap_cnt; ia.ap_idx = ap_idx;
  ia.last = colA; ia.uni = colU; ia.xf = xf;
  ia.rowb0 = rowb6; ia.deg0 = deg6;
  ia.wl1=d_in[3];  ia.bl1=d_in[4];
  ia.wl2=d_in[5];  ia.bl2=d_in[6];
  ia.wl3=d_in[7];  ia.bl3=d_in[8];
  ia.wg1=d_in[9];  ia.bg1=d_in[10];
  ia.wg2=d_in[11]; ia.bg2=d_in[12];
  ia.wg3=d_in[13]; ia.bg3=d_in[14];
  ia.wg4=d_in[15]; ia.bg4=d_in[16];
  ia.wg5=d_in[17]; ia.bg5=d_in[18];
  ia.wg6=d_in[19]; ia.bg6=d_in[20];
  ia.tl1=tl1; ia.tg1=tg1; ia.tl2=tl2; ia.tg2=tg2; ia.tl3=tl3;
  ia.tg3=tg3; ia.tg4=tg4; ia.tg5=tg5; ia.tg6=tg6;
  ia.obl1=obl1; ia.obg1=obg1; ia.obl2=obl2; ia.obg2=obg2; ia.obl3=obl3;
  ia.obg3=obg3; ia.obg4=obg4; ia.obg5=obg5; ia.obg6=obg6;
  ia.flag = dflag;
  input_kernel<<<17152, 256, 0, stream>>>(ia);

  const u64* rb[6]; const int* dg[6];
  for (int s = 0; s < 6; ++s){ rb[s] = rowb6 + (size_t)s*NN*32; dg[s] = deg6 + s*NN; }

  // bit pipeline args: exp_s (s=1..5) with src/dst colA<->colB, uni colU<->colV
  ExpArgs ex[6]; TrArgs tr[6];
  {
    const u64 *src = colA, *uin = colU;
    u64 *dst = colB, *uout = colV;
    for (int s = 1; s < 6; ++s){
      ex[s].cnt = ap_cnt; ex[s].idx = ap_idx;
      ex[s].src = src; ex[s].dst = dst; ex[s].uniIn = uin; ex[s].uniOut = uout;
      tr[s].uni = uout; tr[s].rowb = rowb6 + (size_t)s*NN*32; tr[s].deg = deg6 + s*NN;
      const u64* t1 = src; src = dst; dst = (u64*)t1;
      const u64* t2 = uin; uin = uout; uout = (u64*)t2;
    }
  }
  Piggy pg;

  // ---- stage 0 (F=256); slots carry {exp1},{tr1+exp2},{tr2+exp3},{tr3+exp4} ----
  pg.ea = ex[1]; pg.nexp = 512; pg.ntr = 0;
  hyb_g0<<<128 + 512, 256, 0, stream>>>(xf, tl1, obl1, hF, pg);
  pg.ea = ex[2]; pg.ta = tr[1]; pg.nexp = 512; pg.ntr = 256;
  hyb_g1<<<128 + 768, 256, 0, stream>>>(hF, tg1, dg[0], zs, pg);
  pg.ea = ex[3]; pg.ta = tr[2];
  hyb_p0<<<512 + 768, 256, 0, stream>>>(zs, rb[0], part, pg);
  pg.ea = ex[4]; pg.ta = tr[3];
  hyb_e0<<<2048 + 768, 256, 0, stream>>>(part, zs, hF, obg1, dg[0], xF, pg);

  // ---- stage 1: 16-row dual GEMM (x1 -> h2, z2), 128 host blocks, carries {tr4+exp5}
  pg.ea = ex[5]; pg.ta = tr[4];
  hyb_g2_16<<<128 + 768, 256, 0, stream>>>(xF, tl2, obl2, tg2, dg[1], hF, zs, pg);
  // maggp rb[1] (KS=4, KCH=512) carries {tr5}
  pg.nexp = 0; pg.ntr = 256; pg.ta = tr[5];
  hyb_p1<<<128 + 256, 256, 0, stream>>>(zs, rb[1], part, pg);

  // ---- fused tail: epi(prev stage, KS=4) + next-stage GEMM, 128 blocks each ----
  // epi(stage1: h=h2, obg2, dg[1], 1.0, relu) -> x2 ; dual GEMM tl3/tg3 -> h3, z3
  epieg2_16<<<128, 256, 0, stream>>>(part, zs, hF, obg2, dg[1], 1.0f, xF,
                                     tl3, obl3, tg3, dg[2], hF, zs);
  maggp_kernel<64><<<dim3(32,1,4), 256, 0, stream>>>(zs, rb[2], part, 512);
  // epi(stage2: h=h3, obg3, dg[2], 0.5) -> x3 ; GEMM tg4 -> z4
  epieg1_16<<<128, 256, 0, stream>>>(part, zs, hF, obg3, dg[2], 0.5f, xF,
                                     tg4, dg[3], zs);
  maggp_kernel<64><<<dim3(32,1,4), 256, 0, stream>>>(zs, rb[3], part, 512);
  // epi(stage3: h=x3, obg4, dg[3], 0.5) -> x4 ; GEMM tg5 -> z5
  epieg1_16<<<128, 256, 0, stream>>>(part, zs, xF, obg4, dg[3], 0.5f, xF,
                                     tg5, dg[4], zs);
  maggp_kernel<64><<<dim3(32,1,4), 256, 0, stream>>>(zs, rb[4], part, 512);
  // epi(stage4: h=x4, obg5, dg[4], 0.25) -> x5 ; GEMM tg6 -> z6
  epieg1_16<<<128, 256, 0, stream>>>(part, zs, xF, obg5, dg[4], 0.25f, xF,
                                     tg6, dg[5], zs);
  maggp_kernel<64><<<dim3(32,1,4), 256, 0, stream>>>(zs, rb[5], part, 512);
  // ---- final epilogue -> d_out ----
  magge_kernel<64><<<(NN*64)/256, 256, 0, stream>>>(part, zs, xF, obg6, dg[5], 4,
                                                    0.25f, 0, xF, (float*)d_out);
}

// Round 14
// 259.935 us; speedup vs baseline: 1.0691x; 1.0691x over previous
//
#include <hip/hip_runtime.h>

typedef unsigned short u16;
typedef unsigned int   u32;
typedef unsigned long long u64;
typedef __attribute__((ext_vector_type(8))) short short8;
typedef __attribute__((ext_vector_type(4))) float f32x4;

#define NN 2048
#define LDT 72

__device__ __forceinline__ float b2f(u16 u){ union { u32 i; float f; } x; x.i = ((u32)u)<<16; return x.f; }
__device__ __forceinline__ u16 f2b(float f){
  u32 u = __float_as_uint(f);
  u32 r = (u + 0x7fffu + ((u>>16)&1u)) >> 16;
  return (u16)r;
}
__device__ __forceinline__ float ldf(const void* p, size_t i, int bf){
  return bf ? b2f(((const u16*)p)[i]) : ((const float*)p)[i];
}
__device__ __forceinline__ void splitbf(float v, u16& h, u16& l){
  h = f2b(v);
  l = f2b(v - b2f(h));
}
__device__ __forceinline__ u64 shflx64(u64 x, int m){
  u32 lo = (u32)x, hi = (u32)(x>>32);
  lo = (u32)__shfl_xor((int)lo, m, 64);
  hi = (u32)__shfl_xor((int)hi, m, 64);
  return ((u64)hi<<32) | (u64)lo;
}

// 64x64 in-wave bit transpose: lane t holds column t (bit r = row r) -> row t
__device__ __forceinline__ u64 bittr64(u64 v, int t){
  const u64 MS[6] = {0x00000000FFFFFFFFULL, 0x0000FFFF0000FFFFULL, 0x00FF00FF00FF00FFULL,
                     0x0F0F0F0F0F0F0F0FULL, 0x3333333333333333ULL, 0x5555555555555555ULL};
#pragma unroll
  for (int s5 = 0; s5 < 6; ++s5){
    int jj = 32 >> s5;
    u64 pm = shflx64(v, jj);
    u64 M = MS[s5];
    if ((t & jj) == 0) v = (v &  M) | ((pm &  M) << jj);
    else               v = (v & ~M) | ((pm & ~M) >> jj);
  }
  return v;
}

// ---------------- diagnostic sentinel (f32 out) ------------------------------
__global__ __launch_bounds__(256) void sentinel_kernel(float* __restrict__ out, float val){
  int g = blockIdx.x*256 + threadIdx.x;
  if (g < NN*64) out[g] = val;
}

// ---------------- dtype probe (parallel): fp32 words are 0 / 0x3F800000 -----
__global__ __launch_bounds__(256) void probe_kernel(const u32* __restrict__ ap, int* __restrict__ flag){
  int i = blockIdx.x*256 + threadIdx.x;   // 65536 words
  u32 w = ap[i];
  if (w != 0u && w != 0x3F800000u) atomicOr(flag, 1);
}

// ---------------- fused input processing: csc | negbits+tr0 | prep ----------
struct InputArgs {
  const void *Ap, *An, *x;
  int *ap_cnt, *ap_idx;
  u64 *last, *uni;
  u64* rowb0; int* deg0;      // stage-0 row bits + degree (fused bitstep 0)
  float* xf;
  const void *wl1,*bl1,*wl2,*bl2,*wl3,*bl3,*wg1,*bg1,*wg2,*bg2,*wg3,*bg3,*wg4,*bg4,*wg5,*bg5,*wg6,*bg6;
  float *tl1,*tg1,*tl2,*tg2,*tl3,*tg3,*tg4,*tg5,*tg6;
  float *obl1,*obg1,*obl2,*obg2,*obl3,*obg3,*obg4,*obg5,*obg6;
  const int* flag;
};

__global__ __launch_bounds__(256) void input_kernel(InputArgs a){
  int bf = *a.flag;
  int b = blockIdx.x;
  if (b < 16384){
    size_t e = (size_t)b*256 + threadIdx.x;   // e = k*2048 + j
    int k = (int)(e >> 11), j = (int)(e & 2047);
    if (ldf(a.Ap, e, bf) > 0.f){
      int p = atomicAdd(&a.ap_cnt[j], 1);
      if (p < 64) a.ap_idx[j*64 + p] = k;
    }
  } else if (b < 16640){
    int g = (b - 16384)*256 + threadIdx.x;    // 65536; wave holds 64 consecutive j, same w
    int j = g & 2047, w = g >> 11;
    int lane = threadIdx.x & 63;
    u64 bits = 0;
    for (int bb = 0; bb < 64; ++bb){
      float v = ldf(a.An, (size_t)(w*64 + bb)*NN + j, bf);
      bits |= (u64)(v > 0.f) << bb;
    }
    a.last[(size_t)j*32 + w] = bits;
    a.uni [(size_t)j*32 + w] = bits;
    // fused bitstep 0: transpose the 64x64 tile in-wave, emit rowb[0] + deg[0]
    u64 v = bittr64(bits, lane);
    a.rowb0[(size_t)(w*64 + lane)*32 + (j >> 6)] = v;
    atomicAdd(&a.deg0[w*64 + lane], (int)__popcll(v));
  } else {
    int t = (b - 16640)*256 + threadIdx.x;    // 131072 threads
    for (size_t i = t; i < (size_t)NN*512; i += 131072) a.xf[i] = ldf(a.x, i, bf);
    if (t < 256*512){ int n = t>>9, k = t&511; a.tl1[t] = ldf(a.wl1, (size_t)k*256 + n, bf); }
    if (t < 256*256){ int n = t>>8, k = t&255; a.tg1[t] = ldf(a.wg1, (size_t)k*256 + n, bf); }
    if (t <  64*256){ int n = t>>8, k = t&255; a.tl2[t] = (n < 62) ? ldf(a.wl2, (size_t)k*62 + n, bf) : 0.f; }
    if (t <  64*64){
      int n = t>>6, k = t&63;
      a.tg2[t] = (n < 62 && k < 62) ? ldf(a.wg2, (size_t)k*62 + n, bf) : 0.f;
      a.tl3[t] = (k < 62) ? ldf(a.wl3, (size_t)k*64 + n, bf) : 0.f;
      a.tg3[t] = ldf(a.wg3, (size_t)k*64 + n, bf);
      a.tg4[t] = ldf(a.wg4, (size_t)k*64 + n, bf);
      a.tg5[t] = ldf(a.wg5, (size_t)k*64 + n, bf);
      a.tg6[t] = ldf(a.wg6, (size_t)k*64 + n, bf);
    }
    if (t < 256){ a.obl1[t] = ldf(a.bl1, t, bf); a.obg1[t] = ldf(a.bg1, t, bf); }
    if (t < 64){
      a.obl2[t] = (t < 62) ? ldf(a.bl2, t, bf) : 0.f;
      a.obg2[t] = (t < 62) ? ldf(a.bg2, t, bf) : 0.f;
      a.obl3[t] = ldf(a.bl3, t, bf);
      a.obg3[t] = ldf(a.bg3, t, bf);
      a.obg4[t] = ldf(a.bg4, t, bf);
      a.obg5[t] = ldf(a.bg5, t, bf);
      a.obg6[t] = ldf(a.bg6, t, bf);
    }
  }
}

// --------------- bit expansion (coalesced, 1 wave per column j) -------------
struct ExpArgs { const int *cnt, *idx; const u64* src; u64* dst; const u64* uniIn; u64* uniOut; };
struct TrArgs  { const u64* uni; u64* rowb; int* deg; };

__device__ __forceinline__ void exp_blocks(const ExpArgs& ea, int eb){
  int wave = threadIdx.x >> 6, lane = threadIdx.x & 63;
  int j = eb*4 + wave;                     // eb in [0,512)
  int c = ea.cnt[j]; c = (c > 64) ? 64 : c;
  const int* lst = ea.idx + j*64;
  int wi = lane & 31, half = lane >> 5;
  u64 acc = 0;
  for (int s = half; s < c; s += 2)
    acc |= ea.src[(size_t)lst[s]*32 + wi]; // 32-lane coalesced 256B column read
  acc |= shflx64(acc, 32);
  if (lane < 32){
    ea.dst   [(size_t)j*32 + wi] = acc;
    ea.uniOut[(size_t)j*32 + wi] = ea.uniIn[(size_t)j*32 + wi] | acc;
  }
}

__device__ __forceinline__ void tr_blocks(const TrArgs& ta, int eb){
  int uid = eb*4 + (threadIdx.x >> 6);     // eb in [0,256), uid in [0,1024)
  int wi = uid >> 5, wj = uid & 31;
  int t = threadIdx.x & 63;
  u64 u = ta.uni[(size_t)(wj*64 + t)*32 + wi];
  u64 v = bittr64(u, t);
  ta.rowb[(size_t)(wi*64 + t)*32 + wj] = v;
  atomicAdd(&ta.deg[wi*64 + t], (int)__popcll(v));
}

struct Piggy { ExpArgs ea; TrArgs ta; int nexp, ntr; };
__device__ __forceinline__ void piggy_blocks(const Piggy& pg, int eb){
  if (eb < pg.nexp) exp_blocks(pg.ea, eb);
  else if (eb < pg.nexp + pg.ntr) tr_blocks(pg.ta, eb - pg.nexp);
}

#define MFMA_BF16 __builtin_amdgcn_mfma_f32_16x16x32_bf16

// --------------- split-bf16 MFMA GEMM: C[i][n] = sum_k A[i][k]*Bt[n][k] -----
// MODE 0: + bias[n] ; MODE 1: * 1/sqrt(deg[i]+1)
template<int MODE>
__device__ __forceinline__ void mgemm_core(u16* __restrict__ Ah, u16* __restrict__ Al,
                                           u16* __restrict__ Bh, u16* __restrict__ Bl,
                                           const float* __restrict__ A, const float* __restrict__ Bt,
                                           int N, int K,
                                           const float* __restrict__ bias, const int* __restrict__ deg,
                                           float* __restrict__ outF, int m0, int n0){
  const int tid = threadIdx.x;
  const int wave = tid >> 6, lane = tid & 63;
  const int wm = (wave>>1)*32, wn = (wave&1)*32;
  const int q = lane >> 4, l16 = lane & 15;
  f32x4 acc00 = {}, acc01 = {}, acc10 = {}, acc11 = {};
  const int sr = tid >> 2, sc = (tid & 3)*16;
  for (int k0 = 0; k0 < K; k0 += 64){
    const float* Ag = A  + (size_t)(m0+sr)*K + k0 + sc;
    const float* Bg = Bt + (size_t)(n0+sr)*K + k0 + sc;
#pragma unroll
    for (int v4 = 0; v4 < 4; ++v4){
      float4 av = ((const float4*)Ag)[v4];
      float4 bv = ((const float4*)Bg)[v4];
      int o = sr*LDT + sc + v4*4;
      splitbf(av.x, Ah[o+0], Al[o+0]); splitbf(av.y, Ah[o+1], Al[o+1]);
      splitbf(av.z, Ah[o+2], Al[o+2]); splitbf(av.w, Ah[o+3], Al[o+3]);
      splitbf(bv.x, Bh[o+0], Bl[o+0]); splitbf(bv.y, Bh[o+1], Bl[o+1]);
      splitbf(bv.z, Bh[o+2], Bl[o+2]); splitbf(bv.w, Bh[o+3], Bl[o+3]);
    }
    __syncthreads();
#pragma unroll
    for (int ks = 0; ks < 2; ++ks){
      const int kb = ks*32 + q*8;
      short8 ah0 = *(const short8*)&Ah[(wm      + l16)*LDT + kb];
      short8 al0 = *(const short8*)&Al[(wm      + l16)*LDT + kb];
      short8 ah1 = *(const short8*)&Ah[(wm + 16 + l16)*LDT + kb];
      short8 al1 = *(const short8*)&Al[(wm + 16 + l16)*LDT + kb];
      short8 bh0 = *(const short8*)&Bh[(wn      + l16)*LDT + kb];
      short8 bl0 = *(const short8*)&Bl[(wn      + l16)*LDT + kb];
      short8 bh1 = *(const short8*)&Bh[(wn + 16 + l16)*LDT + kb];
      short8 bl1 = *(const short8*)&Bl[(wn + 16 + l16)*LDT + kb];
      acc00 = MFMA_BF16(ah0, bh0, acc00, 0, 0, 0);
      acc00 = MFMA_BF16(ah0, bl0, acc00, 0, 0, 0);
      acc00 = MFMA_BF16(al0, bh0, acc00, 0, 0, 0);
      acc01 = MFMA_BF16(ah0, bh1, acc01, 0, 0, 0);
      acc01 = MFMA_BF16(ah0, bl1, acc01, 0, 0, 0);
      acc01 = MFMA_BF16(al0, bh1, acc01, 0, 0, 0);
      acc10 = MFMA_BF16(ah1, bh0, acc10, 0, 0, 0);
      acc10 = MFMA_BF16(ah1, bl0, acc10, 0, 0, 0);
      acc10 = MFMA_BF16(al1, bh0, acc10, 0, 0, 0);
      acc11 = MFMA_BF16(ah1, bh1, acc11, 0, 0, 0);
      acc11 = MFMA_BF16(ah1, bl1, acc11, 0, 0, 0);
      acc11 = MFMA_BF16(al1, bh1, acc11, 0, 0, 0);
    }
    __syncthreads();
  }
#pragma unroll
  for (int mi = 0; mi < 2; ++mi)
#pragma unroll
  for (int ni = 0; ni < 2; ++ni){
    f32x4 a = (mi == 0) ? ((ni == 0) ? acc00 : acc01) : ((ni == 0) ? acc10 : acc11);
#pragma unroll
    for (int r = 0; r < 4; ++r){
      int i = m0 + wm + mi*16 + q*4 + r;
      int n = n0 + wn + ni*16 + l16;
      float v = a[r];
      if constexpr (MODE == 0) v += bias[n];
      else                     v *= 1.0f / sqrtf((float)(deg[i] + 1));
      outF[(size_t)i*N + n] = v;
    }
  }
}

// --------------- split-K bitmask-MFMA aggregation (partials) ----------------
template<int F>
__device__ __forceinline__ void maggp_core(const float* __restrict__ zs, const u64* __restrict__ rowb,
                                           float* __restrict__ p, int m0, int n0, int kc0, int KCH){
  const int tid = threadIdx.x;
  const int wave = tid >> 6, lane = tid & 63;
  const int wm = (wave>>1)*32, wn = (wave&1)*32;
  const int q = lane >> 4, l16 = lane & 15;
  f32x4 acc00 = {}, acc01 = {}, acc10 = {}, acc11 = {};
  for (int k0 = kc0; k0 < kc0 + KCH; k0 += 64){
    const int wd = k0 >> 6;
    u64 w0 = rowb[(size_t)(m0 + wm      + l16)*32 + wd];
    u64 w1 = rowb[(size_t)(m0 + wm + 16 + l16)*32 + wd];
#pragma unroll
    for (int ks = 0; ks < 2; ++ks){
      const int kk = ks*32 + q*8;
      u32 by0 = (u32)(w0 >> kk) & 0xFFu;
      u32 by1 = (u32)(w1 >> kk) & 0xFFu;
      short8 a0, a1;
#pragma unroll
      for (int j = 0; j < 8; ++j){
        a0[j] = (short)(((by0 >> j) & 1u) ? 0x3F80 : 0);
        a1[j] = (short)(((by1 >> j) & 1u) ? 0x3F80 : 0);
      }
      const float* B0 = zs + (size_t)(k0 + kk)*F + n0;
      short8 bh0, bl0, bh1, bl1;
#pragma unroll
      for (int j = 0; j < 8; ++j){
        u16 hh, ll;
        splitbf(B0[(size_t)j*F + wn      + l16], hh, ll); bh0[j] = (short)hh; bl0[j] = (short)ll;
        splitbf(B0[(size_t)j*F + wn + 16 + l16], hh, ll); bh1[j] = (short)hh; bl1[j] = (short)ll;
      }
      acc00 = MFMA_BF16(a0, bh0, acc00, 0, 0, 0);
      acc00 = MFMA_BF16(a0, bl0, acc00, 0, 0, 0);
      acc01 = MFMA_BF16(a0, bh1, acc01, 0, 0, 0);
      acc01 = MFMA_BF16(a0, bl1, acc01, 0, 0, 0);
      acc10 = MFMA_BF16(a1, bh0, acc10, 0, 0, 0);
      acc10 = MFMA_BF16(a1, bl0, acc10, 0, 0, 0);
      acc11 = MFMA_BF16(a1, bh1, acc11, 0, 0, 0);
      acc11 = MFMA_BF16(a1, bl1, acc11, 0, 0, 0);
    }
  }
#pragma unroll
  for (int mi = 0; mi < 2; ++mi)
#pragma unroll
  for (int ni = 0; ni < 2; ++ni){
    f32x4 a = (mi == 0) ? ((ni == 0) ? acc00 : acc01) : ((ni == 0) ? acc10 : acc11);
#pragma unroll
    for (int r = 0; r < 4; ++r){
      int i = m0 + wm + mi*16 + q*4 + r;
      int n = n0 + wn + ni*16 + l16;
      p[(size_t)i*F + n] = a[r];
    }
  }
}

// --------------- split-K reduce + GCN epilogue ------------------------------
template<int F>
__device__ __forceinline__ void magge_core(const float* __restrict__ part, const float* __restrict__ zs,
                                           const float* __restrict__ h, const float* __restrict__ bias,
                                           const int* __restrict__ deg, int KS, float wgt, int doRelu,
                                           float* __restrict__ outF, float* __restrict__ outD, int g){
  int n = g & (F - 1);
  int i = g / F;
  float y = 0.f;
  for (int s = 0; s < KS; ++s) y += part[(size_t)s*NN*F + g];
  float di = 1.0f / sqrtf((float)(deg[i] + 1));
  float o = di*(y + zs[g]) + bias[n];
  if (doRelu) o = fmaxf(o, 0.f);
  float xn = h[g] + wgt*o;
  outF[g] = xn;
  if (outD) outD[g] = xn;
}

// =================== standalone wrappers =====================================
template<int F>
__global__ __launch_bounds__(256) void maggp_kernel(const float* zs, const u64* rowb, float* part, int KCH){
  maggp_core<F>(zs, rowb, part + (size_t)blockIdx.z*NN*F,
                blockIdx.x*64, blockIdx.y*64, blockIdx.z*KCH, KCH);
}
template<int F>
__global__ __launch_bounds__(256) void magge_kernel(const float* part, const float* zs, const float* h,
                                                    const float* bias, const int* deg,
                                                    int KS, float wgt, int doRelu,
                                                    float* outF, float* outD){
  magge_core<F>(part, zs, h, bias, deg, KS, wgt, doRelu, outF, outD, blockIdx.x*256 + threadIdx.x);
}

// ===== 16-row block primitives (128-block fused epi+GEMM kernels, F=64) =====
// block: 16 m-rows, 4 waves; wave w owns n-cols [16w,16w+16); nq = wave*16+l16

#define GEMM16(ACC)                                                        \
  _Pragma("unroll")                                                        \
  for (int ks = 0; ks < 2; ++ks){                                          \
    const int kb = ks*32 + q*8;                                            \
    short8 ah = *(const short8*)&Ah[l16*LDT + kb];                         \
    short8 al = *(const short8*)&Al[l16*LDT + kb];                         \
    short8 bh = *(const short8*)&Bh[nq*LDT + kb];                          \
    short8 bl = *(const short8*)&Bl[nq*LDT + kb];                          \
    ACC = MFMA_BF16(ah, bh, ACC, 0, 0, 0);                                 \
    ACC = MFMA_BF16(ah, bl, ACC, 0, 0, 0);                                 \
    ACC = MFMA_BF16(al, bh, ACC, 0, 0, 0);                                 \
  }

#define STAGE_B64(BT)                                                      \
  {                                                                        \
    const int sr = tid >> 2, sc = (tid & 3)*16;                            \
    const float* Bg = (BT) + (size_t)sr*64 + sc;                           \
    _Pragma("unroll")                                                      \
    for (int v4 = 0; v4 < 4; ++v4){                                        \
      float4 bv = ((const float4*)Bg)[v4];                                 \
      int o = sr*LDT + sc + v4*4;                                          \
      splitbf(bv.x, Bh[o+0], Bl[o+0]); splitbf(bv.y, Bh[o+1], Bl[o+1]);    \
      splitbf(bv.z, Bh[o+2], Bl[o+2]); splitbf(bv.w, Bh[o+3], Bl[o+3]);    \
    }                                                                      \
  }

// split-K epilogue for 16 rows: x = h + wgt*relu((sum part + zs)*dinv + bias)
// writes xF and stashes split-bf16 x into Ah/Al (coalesced part reads)
__device__ __forceinline__ void epi16(const float* __restrict__ part, const float* __restrict__ zsP,
                                      const float* __restrict__ hP, const float* __restrict__ biasP,
                                      const int* __restrict__ degP, float wgt,
                                      float* __restrict__ xF, u16* __restrict__ Ah, u16* __restrict__ Al,
                                      int m0, int tid){
#pragma unroll
  for (int pp = 0; pp < 4; ++pp){
    int idx = pp*256 + tid;            // 0..1023 = 16 rows x 64 n
    int il = idx >> 6, n = idx & 63;
    int i = m0 + il;
    size_t g = (size_t)i*64 + n;
    float y = 0.f;
#pragma unroll
    for (int s = 0; s < 8; ++s) y += part[(size_t)s*NN*64 + g];
    float di = 1.0f / sqrtf((float)(degP[i] + 1));
    float o = fmaxf(di*(y + zsP[g]) + biasP[n], 0.f);
    float xv = hP[g] + wgt*o;
    xF[g] = xv;
    u16 hh, ll; splitbf(xv, hh, ll);
    Ah[il*LDT + n] = hh;
    Al[il*LDT + n] = ll;
  }
}

// --------------- fused: prev-stage epilogue + single GEMM (K=64) ------------
__global__ __launch_bounds__(256) void epieg1_16(const float* __restrict__ part, const float* __restrict__ zsP,
                                                 const float* __restrict__ hP, const float* __restrict__ biasP,
                                                 const int* __restrict__ degP, float wgt,
                                                 float* __restrict__ xF,
                                                 const float* __restrict__ BtG, const int* __restrict__ degN,
                                                 float* __restrict__ zsOut){
  __shared__ u16 Ah[16*LDT], Al[16*LDT], Bh[64*LDT], Bl[64*LDT];
  const int m0 = blockIdx.x*16;
  const int tid = threadIdx.x;
  const int wave = tid >> 6, lane = tid & 63;
  const int q = lane >> 4, l16 = lane & 15;
  const int nq = wave*16 + l16;
  epi16(part, zsP, hP, biasP, degP, wgt, xF, Ah, Al, m0, tid);
  STAGE_B64(BtG)
  __syncthreads();
  f32x4 z = {};
  GEMM16(z)
  const int i0 = m0 + q*4;
#pragma unroll
  for (int r = 0; r < 4; ++r)
    zsOut[(size_t)(i0+r)*64 + nq] = z[r] * (1.0f / sqrtf((float)(degN[i0+r] + 1)));
}

// --------------- fused: prev-stage epilogue + DUAL GEMM (K=64) --------------
__global__ __launch_bounds__(256) void epieg2_16(const float* __restrict__ part, const float* __restrict__ zsP,
                                                 const float* __restrict__ hP, const float* __restrict__ biasP,
                                                 const int* __restrict__ degP, float wgt,
                                                 float* __restrict__ xF,
                                                 const float* __restrict__ Bt1, const float* __restrict__ bias1,
                                                 const float* __restrict__ Bt2, const int* __restrict__ degN,
                                                 float* __restrict__ hOut, float* __restrict__ zsOut){
  __shared__ u16 Ah[16*LDT], Al[16*LDT], Bh[64*LDT], Bl[64*LDT];
  const int m0 = blockIdx.x*16;
  const int tid = threadIdx.x;
  const int wave = tid >> 6, lane = tid & 63;
  const int q = lane >> 4, l16 = lane & 15;
  const int nq = wave*16 + l16;
  epi16(part, zsP, hP, biasP, degP, wgt, xF, Ah, Al, m0, tid);
  STAGE_B64(Bt1)
  __syncthreads();
  f32x4 h = {};
  GEMM16(h)
  __syncthreads();       // Ah reads done before restash
#pragma unroll
  for (int r = 0; r < 4; ++r){
    int il = q*4 + r;
    float hv = h[r] + bias1[nq];
    hOut[(size_t)(m0+il)*64 + nq] = hv;
    u16 hh, ll; splitbf(hv, hh, ll);
    Ah[il*LDT + nq] = hh;
    Al[il*LDT + nq] = ll;
  }
  STAGE_B64(Bt2)
  __syncthreads();
  f32x4 z = {};
  GEMM16(z)
  const int i0 = m0 + q*4;
#pragma unroll
  for (int r = 0; r < 4; ++r)
    zsOut[(size_t)(i0+r)*64 + nq] = z[r] * (1.0f / sqrtf((float)(degN[i0+r] + 1)));
}

// =================== hybrid co-launch kernels ================================
__global__ __launch_bounds__(256) void hyb_g0(const float* A, const float* Bt, const float* bias,
                                              float* outF, Piggy pg){
  __shared__ u16 Ah[64*LDT], Al[64*LDT], Bh[64*LDT], Bl[64*LDT];
  int b = blockIdx.x;
  if (b < 128) mgemm_core<0>(Ah, Al, Bh, Bl, A, Bt, 256, 512, bias, nullptr, outF, (b>>2)*64, (b&3)*64);
  else         piggy_blocks(pg, b - 128);
}
__global__ __launch_bounds__(256) void hyb_g1(const float* A, const float* Bt, const int* deg,
                                              float* outF, Piggy pg){
  __shared__ u16 Ah[64*LDT], Al[64*LDT], Bh[64*LDT], Bl[64*LDT];
  int b = blockIdx.x;
  if (b < 128) mgemm_core<1>(Ah, Al, Bh, Bl, A, Bt, 256, 256, nullptr, deg, outF, (b>>2)*64, (b&3)*64);
  else         piggy_blocks(pg, b - 128);
}
__global__ __launch_bounds__(256) void hyb_p0(const float* zs, const u64* rowb, float* part, Piggy pg){
  int b = blockIdx.x;
  if (b < 512){
    int bx = b & 31, by = (b >> 5) & 3, bz = b >> 7;
    maggp_core<256>(zs, rowb, part + (size_t)bz*NN*256, bx*64, by*64, bz*512, 512);
  } else piggy_blocks(pg, b - 512);
}
__global__ __launch_bounds__(256) void hyb_e0(const float* part, const float* zs, const float* h,
                                              const float* bias, const int* deg, float* outF, Piggy pg){
  int b = blockIdx.x;
  if (b < 2048) magge_core<256>(part, zs, h, bias, deg, 4, 1.0f, 1, outF, nullptr, b*256 + threadIdx.x);
  else          piggy_blocks(pg, b - 2048);
}
// stage-1 dual GEMM, 16-row blocks (128 host) || piggy
__global__ __launch_bounds__(256) void hyb_g2_16(const float* __restrict__ A, const float* __restrict__ Bt1,
                                                 const float* __restrict__ bias1,
                                                 const float* __restrict__ Bt2, const int* __restrict__ deg,
                                                 float* __restrict__ hOut, float* __restrict__ zsOut,
                                                 Piggy pg){
  __shared__ u16 Ah[16*LDT], Al[16*LDT], Bh[64*LDT], Bl[64*LDT];
  int b = blockIdx.x;
  if (b >= 128){ piggy_blocks(pg, b - 128); return; }
  const int m0 = b*16;
  const int tid = threadIdx.x;
  const int wave = tid >> 6, lane = tid & 63;
  const int q = lane >> 4, l16 = lane & 15;
  const int nq = wave*16 + l16;
  f32x4 acc = {};
  for (int k0 = 0; k0 < 256; k0 += 64){
    { // stage A 16x64
      const int ar = tid >> 4, ac = (tid & 15)*4;
      float4 av = *(const float4*)&A[(size_t)(m0+ar)*256 + k0 + ac];
      int o = ar*LDT + ac;
      splitbf(av.x, Ah[o+0], Al[o+0]); splitbf(av.y, Ah[o+1], Al[o+1]);
      splitbf(av.z, Ah[o+2], Al[o+2]); splitbf(av.w, Ah[o+3], Al[o+3]);
    }
    { // stage B 64x64 from Bt1 (row-stride 256)
      const int sr = tid >> 2, sc = (tid & 3)*16;
      const float* Bg = Bt1 + (size_t)sr*256 + k0 + sc;
#pragma unroll
      for (int v4 = 0; v4 < 4; ++v4){
        float4 bv = ((const float4*)Bg)[v4];
        int o = sr*LDT + sc + v4*4;
        splitbf(bv.x, Bh[o+0], Bl[o+0]); splitbf(bv.y, Bh[o+1], Bl[o+1]);
        splitbf(bv.z, Bh[o+2], Bl[o+2]); splitbf(bv.w, Bh[o+3], Bl[o+3]);
      }
    }
    __syncthreads();
    GEMM16(acc)
    __syncthreads();
  }
#pragma unroll
  for (int r = 0; r < 4; ++r){
    int il = q*4 + r;
    float hv = acc[r] + bias1[nq];
    hOut[(size_t)(m0+il)*64 + nq] = hv;
    u16 hh, ll; splitbf(hv, hh, ll);
    Ah[il*LDT + nq] = hh;
    Al[il*LDT + nq] = ll;
  }
  STAGE_B64(Bt2)
  __syncthreads();
  f32x4 z = {};
  GEMM16(z)
  const int i0 = m0 + q*4;
#pragma unroll
  for (int r = 0; r < 4; ++r)
    zsOut[(size_t)(i0+r)*64 + nq] = z[r] * (1.0f / sqrtf((float)(deg[i0+r] + 1)));
}
__global__ __launch_bounds__(256) void hyb_p1(const float* zs, const u64* rowb, float* part, Piggy pg){
  int b = blockIdx.x;
  if (b < 256){
    int bx = b & 31, bz = b >> 5;
    maggp_core<64>(zs, rowb, part + (size_t)bz*NN*64, bx*64, 0, bz*256, 256);
  } else piggy_blocks(pg, b - 256);
}

static inline char* wso(void* ws, size_t& off, size_t bytes){
  char* p = (char*)ws + off;
  off += (bytes + 255) & ~(size_t)255;
  return p;
}

extern "C" void kernel_launch(void* const* d_in, const int* in_sizes, int n_in,
                              void* d_out, int out_size, void* d_ws, size_t ws_size,
                              hipStream_t stream){
  // ---- regression guards ----
  static const int EXP_SIZES[21] = {
    2048*512, 2048*2048, 2048*2048,
    512*256, 256, 256*62, 62, 62*64, 64,
    256*256, 256, 62*62, 62, 64*64, 64,
    64*64, 64, 64*64, 64, 64*64, 64
  };
  float sentinel = 0.f;
  if (n_in != 21) sentinel = 8800000.f;
  if (sentinel == 0.f){
    for (int i = 0; i < 21; ++i)
      if (in_sizes[i] != EXP_SIZES[i]){ sentinel = 100000.f*(float)(i+1); break; }
  }
  if (sentinel == 0.f && out_size != 2048*64) sentinel = 6600000.f;

  // ---- workspace layout (zeroed prefix: dflag|ap_cnt|deg6) ----
  size_t off = 0;
  int*   dflag  = (int*)  wso(d_ws, off, 256);
  int*   ap_cnt = (int*)  wso(d_ws, off, NN*4);
  int*   deg6   = (int*)  wso(d_ws, off, (size_t)6*NN*4);
  size_t zero_bytes = off;
  int*   ap_idx = (int*)  wso(d_ws, off, NN*64*4);
  u64*   colA   = (u64*)  wso(d_ws, off, (size_t)NN*32*8);
  u64*   colB   = (u64*)  wso(d_ws, off, (size_t)NN*32*8);
  u64*   colU   = (u64*)  wso(d_ws, off, (size_t)NN*32*8);
  u64*   colV   = (u64*)  wso(d_ws, off, (size_t)NN*32*8);
  u64*   rowb6  = (u64*)  wso(d_ws, off, (size_t)6*NN*32*8);
  float* xf     = (float*)wso(d_ws, off, (size_t)NN*512*4);
  float* part   = (float*)wso(d_ws, off, (size_t)16*NN*64*4);   // 8 MB split-K partials
  float *tl1 = (float*)wso(d_ws, off, 256*512*4), *tg1 = (float*)wso(d_ws, off, 256*256*4);
  float *tl2 = (float*)wso(d_ws, off,  64*256*4), *tg2 = (float*)wso(d_ws, off,  64*64*4);
  float *tl3 = (float*)wso(d_ws, off,   64*64*4), *tg3 = (float*)wso(d_ws, off,  64*64*4);
  float *tg4 = (float*)wso(d_ws, off,   64*64*4), *tg5 = (float*)wso(d_ws, off,  64*64*4);
  float *tg6 = (float*)wso(d_ws, off,   64*64*4);
  float *obl1 = (float*)wso(d_ws, off, 256*4), *obg1 = (float*)wso(d_ws, off, 256*4);
  float *obl2 = (float*)wso(d_ws, off, 64*4),  *obg2 = (float*)wso(d_ws, off, 64*4);
  float *obl3 = (float*)wso(d_ws, off, 64*4),  *obg3 = (float*)wso(d_ws, off, 64*4);
  float *obg4 = (float*)wso(d_ws, off, 64*4),  *obg5 = (float*)wso(d_ws, off, 64*4);
  float *obg6 = (float*)wso(d_ws, off, 64*4);
  float* hF   = (float*)wso(d_ws, off, (size_t)NN*256*4);
  float* zs   = (float*)wso(d_ws, off, (size_t)NN*256*4);
  float* xF   = (float*)wso(d_ws, off, (size_t)NN*256*4);

  if (sentinel == 0.f && off > ws_size) sentinel = 7700000.f;

  if (sentinel != 0.f){
    sentinel_kernel<<<(NN*64 + 255)/256, 256, 0, stream>>>((float*)d_out, sentinel);
    return;
  }

  const void* x_in = d_in[0];
  const void* An   = d_in[1];
  const void* Ap   = d_in[2];

  hipMemsetAsync(d_ws, 0, zero_bytes, stream);   // dflag + ap_cnt + deg6
  probe_kernel<<<256, 256, 0, stream>>>((const u32*)Ap, dflag);

  InputArgs ia;
  ia.Ap = Ap; ia.An = An; ia.x = x_in;
  ia.ap_cnt = ap_cnt; ia.ap_idx = ap_idx;
  ia.last = colA; ia.uni = colU; ia.xf = xf;
  ia.rowb0 = rowb6; ia.deg0 = deg6;
  ia.wl1=d_in[3];  ia.bl1=d_in[4];
  ia.wl2=d_in[5];  ia.bl2=d_in[6];
  ia.wl3=d_in[7];  ia.bl3=d_in[8];
  ia.wg1=d_in[9];  ia.bg1=d_in[10];
  ia.wg2=d_in[11]; ia.bg2=d_in[12];
  ia.wg3=d_in[13]; ia.bg3=d_in[14];
  ia.wg4=d_in[15]; ia.bg4=d_in[16];
  ia.wg5=d_in[17]; ia.bg5=d_in[18];
  ia.wg6=d_in[19]; ia.bg6=d_in[20];
  ia.tl1=tl1; ia.tg1=tg1; ia.tl2=tl2; ia.tg2=tg2; ia.tl3=tl3;
  ia.tg3=tg3; ia.tg4=tg4; ia.tg5=tg5; ia.tg6=tg6;
  ia.obl1=obl1; ia.obg1=obg1; ia.obl2=obl2; ia.obg2=obg2; ia.obl3=obl3;
  ia.obg3=obg3; ia.obg4=obg4; ia.obg5=obg5; ia.obg6=obg6;
  ia.flag = dflag;
  input_kernel<<<17152, 256, 0, stream>>>(ia);

  const u64* rb[6]; const int* dg[6];
  for (int s = 0; s < 6; ++s){ rb[s] = rowb6 + (size_t)s*NN*32; dg[s] = deg6 + s*NN; }

  // bit pipeline args: exp_s (s=1..5) with src/dst colA<->colB, uni colU<->colV
  ExpArgs ex[6]; TrArgs tr[6];
  {
    const u64 *src = colA, *uin = colU;
    u64 *dst = colB, *uout = colV;
    for (int s = 1; s < 6; ++s){
      ex[s].cnt = ap_cnt; ex[s].idx = ap_idx;
      ex[s].src = src; ex[s].dst = dst; ex[s].uniIn = uin; ex[s].uniOut = uout;
      tr[s].uni = uout; tr[s].rowb = rowb6 + (size_t)s*NN*32; tr[s].deg = deg6 + s*NN;
      const u64* t1 = src; src = dst; dst = (u64*)t1;
      const u64* t2 = uin; uin = uout; uout = (u64*)t2;
    }
  }
  Piggy pg;

  // ---- stage 0 (F=256); slots carry {exp1},{tr1+exp2},{tr2+exp3},{tr3+exp4} ----
  pg.ea = ex[1]; pg.nexp = 512; pg.ntr = 0;
  hyb_g0<<<128 + 512, 256, 0, stream>>>(xf, tl1, obl1, hF, pg);
  pg.ea = ex[2]; pg.ta = tr[1]; pg.nexp = 512; pg.ntr = 256;
  hyb_g1<<<128 + 768, 256, 0, stream>>>(hF, tg1, dg[0], zs, pg);
  pg.ea = ex[3]; pg.ta = tr[2];
  hyb_p0<<<512 + 768, 256, 0, stream>>>(zs, rb[0], part, pg);
  pg.ea = ex[4]; pg.ta = tr[3];
  hyb_e0<<<2048 + 768, 256, 0, stream>>>(part, zs, hF, obg1, dg[0], xF, pg);

  // ---- stage 1: 16-row dual GEMM (x1 -> h2, z2), 128 host blocks, carries {tr4+exp5}
  pg.ea = ex[5]; pg.ta = tr[4];
  hyb_g2_16<<<128 + 768, 256, 0, stream>>>(xF, tl2, obl2, tg2, dg[1], hF, zs, pg);
  // maggp rb[1] carries {tr5}
  pg.nexp = 0; pg.ntr = 256; pg.ta = tr[5];
  hyb_p1<<<256 + 256, 256, 0, stream>>>(zs, rb[1], part, pg);

  // ---- fused tail: epi(prev stage) + next-stage GEMM, 128 blocks each ----
  // epi(stage1: h=h2, obg2, dg[1], 1.0, relu) -> x2 ; dual GEMM tl3/tg3 -> h3, z3
  epieg2_16<<<128, 256, 0, stream>>>(part, zs, hF, obg2, dg[1], 1.0f, xF,
                                     tl3, obl3, tg3, dg[2], hF, zs);
  maggp_kernel<64><<<dim3(32,1,8), 256, 0, stream>>>(zs, rb[2], part, 256);
  // epi(stage2: h=h3, obg3, dg[2], 0.5) -> x3 ; GEMM tg4 -> z4
  epieg1_16<<<128, 256, 0, stream>>>(part, zs, hF, obg3, dg[2], 0.5f, xF,
                                     tg4, dg[3], zs);
  maggp_kernel<64><<<dim3(32,1,8), 256, 0, stream>>>(zs, rb[3], part, 256);
  // epi(stage3: h=x3, obg4, dg[3], 0.5) -> x4 ; GEMM tg5 -> z5
  epieg1_16<<<128, 256, 0, stream>>>(part, zs, xF, obg4, dg[3], 0.5f, xF,
                                     tg5, dg[4], zs);
  maggp_kernel<64><<<dim3(32,1,8), 256, 0, stream>>>(zs, rb[4], part, 256);
  // epi(stage4: h=x4, obg5, dg[4], 0.25) -> x5 ; GEMM tg6 -> z6
  epieg1_16<<<128, 256, 0, stream>>>(part, zs, xF, obg5, dg[4], 0.25f, xF,
                                     tg6, dg[5], zs);
  maggp_kernel<64><<<dim3(32,1,8), 256, 0, stream>>>(zs, rb[5], part, 256);
  // ---- final epilogue -> d_out ----
  magge_kernel<64><<<(NN*64)/256, 256, 0, stream>>>(part, zs, xF, obg6, dg[5], 8,
                                                    0.25f, 0, xF, (float*)d_out);
}